// Round 5
// baseline (204.005 us; speedup 1.0000x reference)
//
#include <hip/hip_runtime.h>
#include <hip/hip_bf16.h>
#include <math.h>

typedef float v4f __attribute__((ext_vector_type(4)));
typedef __bf16 bf16x8 __attribute__((ext_vector_type(8)));
typedef __bf16 bf16x4 __attribute__((ext_vector_type(4)));

#define NN   1024
#define INF  128
#define H0C  192
#define H1C  96

// ws byte offsets
#define WS_W0BF   0        // 24576 bf16 (A-frag order, BN0 scale folded)
#define WS_W1BF   49152    // 18432 bf16 (A-frag order, BN1 scale folded)
#define WS_BN0SW  86016    // 192 f32: [q][cm][r] = bias0[16cm+4q+r]
#define WS_BN1SW  86784    // 96 f32:  [q][mt][r] = bias1[16mt+4q+r]
#define WS_WOUTSW 87168    // 96 f32:  [q][mt][r] = wout[16mt+4q+r]
#define WS_CSUM   87552    // 1024 f32 column sums (atomic-accumulated)

// ---------------------------------------------------------------------------
// Prep. A-frag (16x16x32): lane holds A[m=l16][k=quad*8+j];
// flat [(mtile*KS+ks)*64 + lane]*8 + j, m = channel, k = input dim.
// Biases and wout pre-swizzled to C-layout register order [q][mt][r].
// Also zeroes the colsum accumulator for this iteration. [validated round 7]
// ---------------------------------------------------------------------------
__global__ __launch_bounds__(256) void prep_kernel(
    const float* __restrict__ W0, const float* __restrict__ g0,
    const float* __restrict__ b0, const float* __restrict__ m0,
    const float* __restrict__ v0, const float* __restrict__ W1,
    const float* __restrict__ g1, const float* __restrict__ b1,
    const float* __restrict__ m1, const float* __restrict__ v1,
    const float* __restrict__ Wout, char* __restrict__ ws)
{
    int e = blockIdx.x * 256 + threadIdx.x;
    __bf16* w0bf = (__bf16*)(ws + WS_W0BF);
    __bf16* w1bf = (__bf16*)(ws + WS_W1BF);
    float* bn0sw = (float*)(ws + WS_BN0SW);
    float* bn1sw = (float*)(ws + WS_BN1SW);
    float* woutsw = (float*)(ws + WS_WOUTSW);
    float* csum = (float*)(ws + WS_CSUM);
    if (e < 24576) {                       // W0: 12 mtiles x 4 ksteps
        int j = e & 7, lane = (e >> 3) & 63, t = e >> 9;
        int ks = t & 3, mt = t >> 2;
        int c = mt * 16 + (lane & 15);               // m = H0 channel
        int k = ks * 32 + ((lane >> 4) << 3) + j;    // k = input feature
        float s = g0[c] * rsqrtf(v0[c] + 1e-5f);
        w0bf[e] = (__bf16)(W0[c * INF + k] * s);
    } else if (e < 43008) {                // W1: 6 mtiles x 6 ksteps
        int e2 = e - 24576;
        int j = e2 & 7, lane = (e2 >> 3) & 63, t = e2 >> 9;
        int ks = t % 6, mt = t / 6;
        int c = mt * 16 + (lane & 15);               // m = H1 channel
        int k = ks * 32 + ((lane >> 4) << 3) + j;    // k = H0 channel
        float s = g1[c] * rsqrtf(v1[c] + 1e-5f);
        w1bf[e2] = (__bf16)(W1[c * H0C + k] * s);
    } else if (e < 43200) {                // bn0 bias swizzled [q][cm][r]
        int e3 = e - 43008;
        int q = e3 / 48, rem = e3 % 48, cm = rem >> 2, r = rem & 3;
        int c = cm * 16 + q * 4 + r;
        float s = g0[c] * rsqrtf(v0[c] + 1e-5f);
        bn0sw[e3] = b0[c] - m0[c] * s;
    } else if (e < 43296) {                // bn1 bias swizzled [q][mt][r]
        int e4 = e - 43200;
        int q = e4 / 24, rem = e4 % 24, mt = rem >> 2, r = rem & 3;
        int c = mt * 16 + q * 4 + r;
        float s = g1[c] * rsqrtf(v1[c] + 1e-5f);
        bn1sw[e4] = b1[c] - m1[c] * s;
    } else if (e < 43392) {                // wout swizzled [q][mt][r]
        int e5 = e - 43296;
        int q = e5 / 24, rem = e5 % 24, mt = rem >> 2, r = rem & 3;
        woutsw[e5] = Wout[mt * 16 + q * 4 + r];
    } else if (e < 44416) {                // zero colsum accumulator
        csum[e - 43392] = 0.f;
    }
}

// ---------------------------------------------------------------------------
// Main kernel, R17: half-tile blocks (4 j-rows), NO cross-wave epilogue.
// Post-mortem R15/R16: both correctness failures shared the restructured
// pbuf/tail epilogue (runtime-indexed part[quad], predicated LDS combine);
// R17 removes that surface entirely. Layer 2 gives each wave ONE j-column
// with the FULL W1 (R13's validated pattern): after shfl_xor 16/32 every
// lane holds the final z -> direct quad0/quad1 stores exactly like R13.
// LDS = 64*400 = 25600B -> 6 blocks/CU -> 24 waves/CU (vs 12 in R13/R14),
// attacking the measured latency-bound regime (Occ 27%, MfmaUtil 22).
//   layer-1: wave = mtg (channel group): 3 mt x 4 nt x 4 ks = 48 MFMA
//   layer-2: wave = j-col: 6 mt x 1 nt x 6 ks = 36 MFMA (full W1, L1-hot)
// Fused csum: 4 scalar direct atomics + 4 vector mirror atomics per block;
// exactly-once via the tile-level dedup predicate (unchanged by halving).
// ---------------------------------------------------------------------------
__global__ __launch_bounds__(256, 6) void edgenet_main(
    const float* __restrict__ feat, const char* __restrict__ ws,
    const float* __restrict__ boutp, float* __restrict__ sim_out,
    float* __restrict__ csum)
{
    __shared__ __align__(16) char smem[25600];   // X (17408) then H0 overlay
    const int tid = threadIdx.x;
    const int lane = tid & 63;
    const int wave = tid >> 6;
    const int l16 = lane & 15;
    const int quad = lane >> 4;

    // decode triangular tile id -> (bi, bj): cum(bi) = bi*(129-bi)  [R2-verified]
    const int id = blockIdx.x >> 1;
    const int half = blockIdx.x & 1;
    int bi = (int)((129.0f - sqrtf(16641.0f - 4.0f * (float)id)) * 0.5f);
    while (bi > 0 && bi * (129 - bi) > id) --bi;
    while ((bi + 1) * (128 - bi) <= id) ++bi;
    const int bj = 2 * bi + (id - bi * (129 - bi));
    const int i0 = bi << 4;
    const int j0h = (bj << 3) + half * 4;   // this block's 4 j-rows

    const bf16x8* w0v = (const bf16x8*)(ws + WS_W0BF);
    const bf16x8* w1v = (const bf16x8*)(ws + WS_W1BF);
    const float* bn0sw = (const float*)(ws + WS_BN0SW);
    const float* bn1sw = (const float*)(ws + WS_BN1SW);

    // ---- X gen: 64 rows = 4 j-rows x 16 i; thread (ii, fblk) streams 4 fj --
    {
        int ii = tid & 15, fblk = tid >> 4;
        const float* fi = feat + (i0 + ii) * INF + fblk * 8;
        float4 a0 = *(const float4*)fi;
        float4 a1 = *(const float4*)(fi + 4);
        const float* fj = feat + j0h * INF + fblk * 8;
        char* sp = smem + ii * 272 + fblk * 16;
        #pragma unroll
        for (int jj = 0; jj < 4; ++jj) {
            float4 q0 = *(const float4*)fj;
            float4 q1 = *(const float4*)(fj + 4);
            bf16x8 x;
            x[0] = (__bf16)fabsf(a0.x - q0.x);
            x[1] = (__bf16)fabsf(a0.y - q0.y);
            x[2] = (__bf16)fabsf(a0.z - q0.z);
            x[3] = (__bf16)fabsf(a0.w - q0.w);
            x[4] = (__bf16)fabsf(a1.x - q1.x);
            x[5] = (__bf16)fabsf(a1.y - q1.y);
            x[6] = (__bf16)fabsf(a1.z - q1.z);
            x[7] = (__bf16)fabsf(a1.w - q1.w);
            *(bf16x8*)sp = x;
            fj += INF;
            sp += 16 * 272;
        }
    }
    __syncthreads();

    // ---- Layer 1: wave = channel group mtg; 3 mt x 4 nt x 4 ks ----
    const int mtg = wave;
    bf16x4 pk[3][4];
    {
        v4f acc[3][4];
        #pragma unroll
        for (int mt = 0; mt < 3; ++mt) {
            v4f bb = *(const v4f*)(bn0sw + (quad * 12 + mtg * 3 + mt) * 4);
            #pragma unroll
            for (int nt = 0; nt < 4; ++nt)
                acc[mt][nt] = bb;
        }
        #pragma unroll
        for (int ks = 0; ks < 4; ++ks) {
            bf16x8 w0a = w0v[((mtg * 3 + 0) * 4 + ks) * 64 + lane];
            bf16x8 w0b = w0v[((mtg * 3 + 1) * 4 + ks) * 64 + lane];
            bf16x8 w0c = w0v[((mtg * 3 + 2) * 4 + ks) * 64 + lane];
            #pragma unroll
            for (int nt = 0; nt < 4; ++nt) {
                bf16x8 xk = *(const bf16x8*)(smem +
                    (nt * 16 + l16) * 272 + ks * 64 + quad * 16);
                acc[0][nt] = __builtin_amdgcn_mfma_f32_16x16x32_bf16(
                    w0a, xk, acc[0][nt], 0, 0, 0);
                acc[1][nt] = __builtin_amdgcn_mfma_f32_16x16x32_bf16(
                    w0b, xk, acc[1][nt], 0, 0, 0);
                acc[2][nt] = __builtin_amdgcn_mfma_f32_16x16x32_bf16(
                    w0c, xk, acc[2][nt], 0, 0, 0);
            }
        }
        // leaky + pack -> bf16 VGPRs (carried across the overlay barrier)
        #pragma unroll
        for (int mt = 0; mt < 3; ++mt)
            #pragma unroll
            for (int nt = 0; nt < 4; ++nt) {
                bf16x4 p;
                #pragma unroll
                for (int r = 0; r < 4; ++r) {
                    float v = acc[mt][nt][r];
                    v = fmaxf(v, 0.01f * v);
                    p[r] = (__bf16)v;
                }
                pk[mt][nt] = p;
            }
    }
    __syncthreads();   // all X reads done; H0 may overlay

    // ---- H0 write: 12 ds_write_b64 (channels by mtg) ----
    #pragma unroll
    for (int mt = 0; mt < 3; ++mt) {
        int chb = (mtg * 3 + mt) * 16 + quad * 4;
        #pragma unroll
        for (int nt = 0; nt < 4; ++nt)
            *(bf16x4*)(smem + (nt * 16 + l16) * 400 + chb * 2) = pk[mt][nt];
    }
    __syncthreads();   // H0 complete (cross-wave channels)

    // ---- Layer 2: wave owns ONE j-col; full W1 (6 mt x 6 ks), 36 MFMA ----
    v4f acc2[6];
    #pragma unroll
    for (int mt = 0; mt < 6; ++mt)
        acc2[mt] = *(const v4f*)(bn1sw + (quad * 6 + mt) * 4);
    #pragma unroll
    for (int ks = 0; ks < 6; ++ks) {
        bf16x8 hb = *(const bf16x8*)(smem +
            (wave * 16 + l16) * 400 + ks * 64 + quad * 16);
        #pragma unroll
        for (int mt = 0; mt < 6; ++mt) {
            bf16x8 w = w1v[(mt * 6 + ks) * 64 + lane];
            acc2[mt] = __builtin_amdgcn_mfma_f32_16x16x32_bf16(
                w, hb, acc2[mt], 0, 0, 0);
        }
    }

    // ---- epilogue: leaky + dot(wout) + shfl reduce; every lane holds z ----
    const float* woutsw = (const float*)(ws + WS_WOUTSW);
    float part = 0.f;
    #pragma unroll
    for (int mt = 0; mt < 6; ++mt) {
        v4f wo = *(const v4f*)(woutsw + (quad * 6 + mt) * 4);
        #pragma unroll
        for (int r = 0; r < 4; ++r) {
            float v = acc2[mt][r];
            v = fmaxf(v, 0.01f * v);
            part = fmaf(v, wo[r], part);
        }
    }
    part += __shfl_xor(part, 16, 64);
    part += __shfl_xor(part, 32, 64);
    const int jg = j0h + wave;
    float sv = 1.f / (1.f + expf(-(part + boutp[0])));
    if (quad == 0)
        sim_out[(i0 + l16) * NN + jg] = sv;          // direct (column)
    else if (quad == 1)
        sim_out[jg * NN + (i0 + l16)] = sv;          // mirror (64B run)

    // ---- fused csum (exact dedup; full-wave shfls, predicated atomics) ----
    float s = sv;
    s += __shfl_xor(s, 1, 64);
    s += __shfl_xor(s, 2, 64);
    s += __shfl_xor(s, 4, 64);
    s += __shfl_xor(s, 8, 64);
    if (lane == 0) atomicAdd(csum + jg, s);          // direct colsum, 1/wave
    // mirror cell (a,b) = (jg, i0+l16) counts iff NOT direct-covered:
    bool dup = ((i0 + l16) >> 3) >= 2 * (jg >> 4);
    float ms = dup ? 0.f : sv;
    if (quad == 1) atomicAdd(csum + i0 + l16, ms);   // vector atomic, 1/wave
}

// ---------------------------------------------------------------------------
// edge[i][j] = (sim + eye + 1e-6) / (colsum[j] + 1 + N*1e-6).
// ---------------------------------------------------------------------------
__global__ __launch_bounds__(256) void edge_kernel(
    const float* __restrict__ csum, const float* __restrict__ sim,
    float* __restrict__ edge)
{
    int i = blockIdx.x;
    int jc = threadIdx.x << 2;
    const float cadd = 1.0f + (float)NN * 1e-6f;
    float4 cs = *(const float4*)(csum + jc);
    float4 w;
    w.x = 1.0f / (cs.x + cadd);
    w.y = 1.0f / (cs.y + cadd);
    w.z = 1.0f / (cs.z + cadd);
    w.w = 1.0f / (cs.w + cadd);
    float4 s = *(const float4*)(sim + i * NN + jc);
    float4 o;
    o.x = (s.x + (i == jc + 0 ? 1.f : 0.f) + 1e-6f) * w.x;
    o.y = (s.y + (i == jc + 1 ? 1.f : 0.f) + 1e-6f) * w.y;
    o.z = (s.z + (i == jc + 2 ? 1.f : 0.f) + 1e-6f) * w.z;
    o.w = (s.w + (i == jc + 3 ? 1.f : 0.f) + 1e-6f) * w.w;
    *(float4*)(edge + i * NN + jc) = o;
}

extern "C" void kernel_launch(void* const* d_in, const int* in_sizes, int n_in,
                              void* d_out, int out_size, void* d_ws, size_t ws_size,
                              hipStream_t stream)
{
    const float* feat = (const float*)d_in[0];
    const float* W0   = (const float*)d_in[1];
    const float* g0   = (const float*)d_in[2];
    const float* b0   = (const float*)d_in[3];
    const float* m0   = (const float*)d_in[4];
    const float* v0   = (const float*)d_in[5];
    const float* W1   = (const float*)d_in[6];
    const float* g1   = (const float*)d_in[7];
    const float* b1   = (const float*)d_in[8];
    const float* m1   = (const float*)d_in[9];
    const float* v1   = (const float*)d_in[10];
    const float* Wout = (const float*)d_in[11];
    const float* bout = (const float*)d_in[12];
    char* ws = (char*)d_ws;
    float* edge = (float*)d_out;
    float* sim  = edge + NN * NN;
    float* csum = (float*)(ws + WS_CSUM);

    prep_kernel<<<dim3(174), dim3(256), 0, stream>>>(
        W0, g0, b0, m0, v0, W1, g1, b1, m1, v1, Wout, ws);
    edgenet_main<<<dim3(8320), dim3(256), 0, stream>>>(feat, ws, bout, sim, csum);
    edge_kernel<<<dim3(1024), dim3(256), 0, stream>>>(csum, sim, edge);
}